// Round 1
// 411.946 us; speedup vs baseline: 1.0018x; 1.0018x over previous
//
#include <hip/hip_runtime.h>

#define DEVINL __device__ __forceinline__

typedef unsigned short u16;
typedef float f32x4 __attribute__((ext_vector_type(4)));
typedef __bf16 bf16x8 __attribute__((ext_vector_type(8)));

constexpr int N_ = 1024, B_ = 4, C_ = 1024, H_ = 8, D_ = 128;
constexpr int NB = N_ * B_;   // 4096 rows
constexpr int BH = B_ * H_;   // 32 head-batches

// ---------- helpers ----------
DEVINL u16 f2bf(float f) {            // RNE f32 -> bf16 (inputs finite)
  unsigned u = __builtin_bit_cast(unsigned, f);
  u += 0x7fffu + ((u >> 16) & 1u);
  return (u16)(u >> 16);
}
DEVINL float bf2f(u16 v) { return __builtin_bit_cast(float, ((unsigned)v) << 16); }

typedef __attribute__((address_space(1))) void gv_t;
typedef __attribute__((address_space(3))) void lv_t;
DEVINL void gload16(const void* g, void* l) {   // async global->LDS, 16B/lane
  __builtin_amdgcn_global_load_lds((gv_t*)(unsigned long long)g,
                                   (lv_t*)(unsigned)(unsigned long long)l, 16, 0, 0);
}
DEVINL bf16x8 ld_frag(const u16* p) { return *(const bf16x8*)p; }
DEVINL f32x4 mfma16(bf16x8 a, bf16x8 b, f32x4 c) {
  return __builtin_amdgcn_mfma_f32_16x16x32_bf16(a, b, c, 0, 0, 0);
}

// ---------- K0: fp32 -> bf16 convert ----------
struct ConvArgs { const float* s[10]; u16* d[10]; int n[10]; };

__global__ __launch_bounds__(256) void k_convert(ConvArgs a) {
  const int which = blockIdx.y;
  const int i = (blockIdx.x * 256 + threadIdx.x) * 8;
  if (i >= a.n[which]) return;
  const float* s = a.s[which] + i;
  float4 v0 = *(const float4*)s;
  float4 v1 = *(const float4*)(s + 4);
  union { uint4 v; u16 r[8]; } u;
  u.r[0] = f2bf(v0.x); u.r[1] = f2bf(v0.y); u.r[2] = f2bf(v0.z); u.r[3] = f2bf(v0.w);
  u.r[4] = f2bf(v1.x); u.r[5] = f2bf(v1.y); u.r[6] = f2bf(v1.z); u.r[7] = f2bf(v1.w);
  *(uint4*)(a.d[which] + i) = u.v;
}

// ---------- K1: projection GEMM + fused L2-norm ----------
// Y[r,d] = sum_c X[r,c] * W[d,c]; col-tile 128 == one head, so per-row L2 norm
// over d is completed in-block (z<4 -> q/k tensors get normalized, z==4 is v).
struct ProjArgs { const u16* X[5]; const u16* W[5]; u16* O[5]; };

__global__ __launch_bounds__(256) void k_proj(ProjArgs a) {
  __shared__ u16 lA[128 * 64];
  __shared__ u16 lB[128 * 64];
  __shared__ float lred[128][2];
  const int tid = threadIdx.x, w = tid >> 6, lane = tid & 63;
  const int qd = lane >> 4, m16 = lane & 15;
  const int wr = w >> 1, wc = w & 1;
  const int r0 = blockIdx.y * 128, d0 = blockIdx.x * 128;
  const u16* __restrict__ X = a.X[blockIdx.z];
  const u16* __restrict__ W = a.W[blockIdx.z];
  u16* __restrict__ O = a.O[blockIdx.z];
  const bool donorm = blockIdx.z < 4;

  f32x4 acc[4][4];
  const f32x4 fz = {0.f, 0.f, 0.f, 0.f};
#pragma unroll
  for (int i = 0; i < 4; ++i)
#pragma unroll
    for (int j = 0; j < 4; ++j) acc[i][j] = fz;

  for (int k0 = 0; k0 < C_; k0 += 64) {
    __syncthreads();
#pragma unroll
    for (int i = 0; i < 4; ++i) {
      int p = i * 256 + tid, row = p >> 3, cp = p & 7, cl = cp ^ (row & 7);
      gload16(X + (size_t)(r0 + row) * C_ + k0 + cl * 8, &lA[p * 8]);
    }
#pragma unroll
    for (int i = 0; i < 4; ++i) {
      int p = i * 256 + tid, row = p >> 3, cp = p & 7, cl = cp ^ (row & 7);
      gload16(W + (size_t)(d0 + row) * C_ + k0 + cl * 8, &lB[p * 8]);
    }
    __syncthreads();
#pragma unroll
    for (int ks = 0; ks < 2; ++ks) {
      bf16x8 af[4], bfr[4];
#pragma unroll
      for (int t = 0; t < 4; ++t) {
        int row = wr * 64 + t * 16 + m16;
        af[t] = ld_frag(&lA[row * 64 + (((ks * 4 + qd) ^ (row & 7)) * 8)]);
        int col = wc * 64 + t * 16 + m16;
        bfr[t] = ld_frag(&lB[col * 64 + (((ks * 4 + qd) ^ (col & 7)) * 8)]);
      }
#pragma unroll
      for (int rt = 0; rt < 4; ++rt)
#pragma unroll
        for (int ct = 0; ct < 4; ++ct)
          acc[rt][ct] = mfma16(af[rt], bfr[ct], acc[rt][ct]);
    }
  }
  // fused L2-norm over the 128-col (= head dim) tile
  if (donorm) {
    float s[4][4];
#pragma unroll
    for (int rt = 0; rt < 4; ++rt)
#pragma unroll
      for (int rg = 0; rg < 4; ++rg) {
        float t = 0.f;
#pragma unroll
        for (int ct = 0; ct < 4; ++ct) t += acc[rt][ct][rg] * acc[rt][ct][rg];
        s[rt][rg] = t;
      }
#pragma unroll
    for (int off = 1; off < 16; off <<= 1)
#pragma unroll
      for (int rt = 0; rt < 4; ++rt)
#pragma unroll
        for (int rg = 0; rg < 4; ++rg) s[rt][rg] += __shfl_xor(s[rt][rg], off);
    if (m16 == 0) {
#pragma unroll
      for (int rt = 0; rt < 4; ++rt)
#pragma unroll
        for (int rg = 0; rg < 4; ++rg)
          lred[wr * 64 + rt * 16 + qd * 4 + rg][wc] = s[rt][rg];
    }
  }
  __syncthreads();
  float inv[4][4];
#pragma unroll
  for (int rt = 0; rt < 4; ++rt)
#pragma unroll
    for (int rg = 0; rg < 4; ++rg) {
      if (donorm) {
        int row = wr * 64 + rt * 16 + qd * 4 + rg;
        inv[rt][rg] = rsqrtf(lred[row][0] + lred[row][1]);
      } else inv[rt][rg] = 1.0f;
    }
  // epilogue: rows r = n*B+b ; cols = h*128+d ; write (B,H,N,D) bf16
#pragma unroll
  for (int rt = 0; rt < 4; ++rt)
#pragma unroll
    for (int ct = 0; ct < 4; ++ct)
#pragma unroll
      for (int rg = 0; rg < 4; ++rg) {
        int row = r0 + wr * 64 + rt * 16 + qd * 4 + rg;
        int col = d0 + wc * 64 + ct * 16 + m16;
        int n = row >> 2, b = row & 3, h = col >> 7, d = col & 127;
        O[(((size_t)(b * H_ + h)) * N_ + n) * D_ + d] = f2bf(acc[rt][ct][rg] * inv[rt][rg]);
      }
}

// ---------- K3: v (B,H,N,D) -> v_t (B,H,D,N) ----------
__global__ __launch_bounds__(256) void k_transpose(const u16* __restrict__ v,
                                                   u16* __restrict__ vt) {
  __shared__ u16 tile[128][65];
  const int bh = blockIdx.y, n0 = blockIdx.x * 64;
  const u16* src = v + (size_t)bh * N_ * D_;
  u16* dst = vt + (size_t)bh * D_ * N_;
  union U8 { uint4 v; u16 s[8]; };
#pragma unroll
  for (int it = 0; it < 4; ++it) {
    int c = it * 256 + threadIdx.x;
    int n = c >> 4, dc = (c & 15) * 8;
    U8 u; u.v = *(const uint4*)(src + (size_t)(n0 + n) * D_ + dc);
#pragma unroll
    for (int j = 0; j < 8; ++j) tile[dc + j][n] = u.s[j];
  }
  __syncthreads();
#pragma unroll
  for (int it = 0; it < 4; ++it) {
    int c = it * 256 + threadIdx.x;
    int d = c >> 3, nc = (c & 7) * 8;
    U8 u;
#pragma unroll
    for (int j = 0; j < 8; ++j) u.s[j] = tile[d][nc + j];
    *(uint4*)(dst + (size_t)d * N_ + n0 + nc) = u.v;
  }
}

// ---------- K4: fused stats + emit + PV (S^T orientation, 32-row strips) ----------
// One block owns a 32-row n-strip of one (b,h). Loop 1 sweeps all m computing
// Sr^T,Sc^T once, exp -> packed bf16 kept in REGISTERS (16 vals/thread/mt/type),
// accumulating softmax denominators. Loop 2 (no staging, no S-MFMA) normalizes,
// stores attn, and does PV via an LDS cross-wave redistribution of P.
__global__ __launch_bounds__(256, 2) void k_attn(const u16* __restrict__ qr,
                                                 const u16* __restrict__ kr,
                                                 const u16* __restrict__ qc,
                                                 const u16* __restrict__ kc,
                                                 const u16* __restrict__ vt,
                                                 float* __restrict__ out0,
                                                 float* __restrict__ out1) {
  __shared__ u16 lK[2][128 * 128];  // 64 KB: [0]=kr tile, [1]=kc tile (128m x 128d)
  __shared__ u16 lP[32 * 136];      // 8.5 KB attn bf16, [n][m] A-layout (pad 8)
  __shared__ float lred[2][4][32];  // 1 KB denominator partials
  const int flat = blockIdx.x + (blockIdx.y << 5);
  const int xcd = flat & 7, kk = flat >> 3;
  const int bh = (xcd << 2) + (kk >> 5);
  const int n0 = (kk & 31) * 32;
  const int b = bh >> 3, h = bh & 7;
  const size_t base = (size_t)bh * N_ * D_;
  const int tid = threadIdx.x, w = tid >> 6, lane = tid & 63;
  const int qd = lane >> 4, m16 = lane & 15;

  // Q fragments (B-operand layout): [type][ct 2][ks 4]
  bf16x8 qf[2][2][4];
#pragma unroll
  for (int ct = 0; ct < 2; ++ct)
#pragma unroll
    for (int ks = 0; ks < 4; ++ks) {
      size_t ro = base + (size_t)(n0 + ct * 16 + m16) * D_ + ks * 32 + qd * 8;
      qf[0][ct][ks] = ld_frag(qr + ro);
      qf[1][ct][ks] = ld_frag(qc + ro);
    }

  // packed exp(S) bf16 held in registers for the whole strip:
  // [type][mt][rt][ct] -> 4 bf16 (uint2) = 128 VGPRs total
  uint2 pst[2][8][2][2];
  float psum[2][2] = {{0.f, 0.f}, {0.f, 0.f}};
  const f32x4 fz = {0.f, 0.f, 0.f, 0.f};

  // ---- loop 1: S once, exp -> regs, accumulate denominators ----
#pragma unroll
  for (int mt = 0; mt < 8; ++mt) {
    const int m0 = mt * 128;
    __syncthreads();
#pragma unroll
    for (int i = 0; i < 8; ++i) {
      int p = i * 256 + tid, row = p >> 4, cp = p & 15, cl = cp ^ (row & 15);
      gload16(kr + base + (size_t)(m0 + row) * D_ + cl * 8, &lK[0][p * 8]);
    }
#pragma unroll
    for (int i = 0; i < 8; ++i) {
      int p = i * 256 + tid, row = p >> 4, cp = p & 15, cl = cp ^ (row & 15);
      gload16(kc + base + (size_t)(m0 + row) * D_ + cl * 8, &lK[1][p * 8]);
    }
    __syncthreads();
#pragma unroll
    for (int ty = 0; ty < 2; ++ty) {
#pragma unroll
      for (int rt = 0; rt < 2; ++rt) {
        bf16x8 af[4];
        const int mrow = w * 32 + rt * 16 + m16;
#pragma unroll
        for (int ks = 0; ks < 4; ++ks)
          af[ks] = ld_frag(&lK[ty][mrow * 128 + (((ks * 4 + qd) ^ (mrow & 15)) * 8)]);
#pragma unroll
        for (int ct = 0; ct < 2; ++ct) {
          f32x4 acc = fz;
#pragma unroll
          for (int ks = 0; ks < 4; ++ks) acc = mfma16(af[ks], qf[ty][ct][ks], acc);
          union { uint2 u; u16 s[4]; } pk;
          float loc = 0.f;
#pragma unroll
          for (int rg = 0; rg < 4; ++rg) {
            float e = __expf(acc[rg]);
            loc += e;
            pk.s[rg] = f2bf(e);
          }
          psum[ty][ct] += loc;
          pst[ty][mt][rt][ct] = pk.u;
        }
      }
    }
  }

  // ---- denominator reduction: over qd (shfl) then over waves (LDS) ----
#pragma unroll
  for (int ty = 0; ty < 2; ++ty)
#pragma unroll
    for (int ct = 0; ct < 2; ++ct) {
      psum[ty][ct] += __shfl_xor(psum[ty][ct], 16);
      psum[ty][ct] += __shfl_xor(psum[ty][ct], 32);
    }
  if (qd == 0) {
#pragma unroll
    for (int ty = 0; ty < 2; ++ty)
#pragma unroll
      for (int ct = 0; ct < 2; ++ct) lred[ty][w][ct * 16 + m16] = psum[ty][ct];
  }
  __syncthreads();
  float il[2][2];
#pragma unroll
  for (int ty = 0; ty < 2; ++ty)
#pragma unroll
    for (int ct = 0; ct < 2; ++ct) {
      int n = ct * 16 + m16;
      il[ty][ct] = 0.5f / (lred[ty][0][n] + lred[ty][1][n] + lred[ty][2][n] + lred[ty][3][n]);
    }

  f32x4 xacc[2][2];
#pragma unroll
  for (int ct = 0; ct < 2; ++ct)
#pragma unroll
    for (int dt = 0; dt < 2; ++dt) xacc[ct][dt] = fz;

  float* attn = out1 + (size_t)bh * N_ * N_;
  const u16* vtb = vt + (size_t)bh * D_ * N_;

  // ---- loop 2: normalize, store attn, PV (no staging, no S recompute) ----
#pragma unroll
  for (int mt = 0; mt < 8; ++mt) {
    const int m0 = mt * 128;
    __syncthreads();   // lP free (prev PV done); also orders lred reads on mt=0
#pragma unroll
    for (int rt = 0; rt < 2; ++rt)
#pragma unroll
      for (int ct = 0; ct < 2; ++ct) {
        union { uint2 u; u16 s[4]; } ur, uc, pk;
        ur.u = pst[0][mt][rt][ct];
        uc.u = pst[1][mt][rt][ct];
        f32x4 pv;
#pragma unroll
        for (int rg = 0; rg < 4; ++rg) {
          pv[rg] = bf2f(ur.s[rg]) * il[0][ct] + bf2f(uc.s[rg]) * il[1][ct];
          pk.s[rg] = f2bf(pv[rg]);
        }
        const int nrow = n0 + ct * 16 + m16;
        const int mcol = m0 + w * 32 + rt * 16 + qd * 4;
        *(f32x4*)(attn + (size_t)nrow * N_ + mcol) = pv;
        *(uint2*)&lP[(ct * 16 + m16) * 136 + w * 32 + rt * 16 + qd * 4] = pk.u;
      }
    __syncthreads();
#pragma unroll
    for (int ks = 0; ks < 4; ++ks) {
      bf16x8 pa[2], vb[2];
#pragma unroll
      for (int ct = 0; ct < 2; ++ct)
        pa[ct] = ld_frag(&lP[(ct * 16 + m16) * 136 + ks * 32 + qd * 8]);
#pragma unroll
      for (int dt = 0; dt < 2; ++dt)
        vb[dt] = ld_frag(vtb + (size_t)(w * 32 + dt * 16 + m16) * N_ + m0 + ks * 32 + qd * 8);
#pragma unroll
      for (int ct = 0; ct < 2; ++ct)
#pragma unroll
        for (int dt = 0; dt < 2; ++dt)
          xacc[ct][dt] = mfma16(pa[ct], vb[dt], xacc[ct][dt]);
    }
  }
  // epilogue: x -> out0 (N,B,C)
#pragma unroll
  for (int ct = 0; ct < 2; ++ct)
#pragma unroll
    for (int dt = 0; dt < 2; ++dt)
#pragma unroll
      for (int rg = 0; rg < 4; ++rg) {
        int n = n0 + ct * 16 + qd * 4 + rg;
        int d = w * 32 + dt * 16 + m16;
        out0[((size_t)n * B_ + b) * C_ + h * 128 + d] = xacc[ct][dt][rg];
      }
}

// ---------- launch ----------
extern "C" void kernel_launch(void* const* d_in, const int* in_sizes, int n_in,
                              void* d_out, int out_size, void* d_ws, size_t ws_size,
                              hipStream_t stream) {
  (void)in_sizes; (void)n_in; (void)out_size; (void)ws_size;
  const float* in_f[10];
  for (int i = 0; i < 10; ++i) in_f[i] = (const float*)d_in[i];

  u16* ws = (u16*)d_ws;
  u16* Xc[5], *Wc[5], *P[5];
  for (int i = 0; i < 5; ++i) Xc[i] = ws + (size_t)i * NB * C_;
  u16* wbase = ws + (size_t)5 * NB * C_;
  for (int i = 0; i < 5; ++i) Wc[i] = wbase + (size_t)i * C_ * C_;
  u16* pbase = wbase + (size_t)5 * C_ * C_;
  for (int i = 0; i < 5; ++i) P[i] = pbase + (size_t)i * BH * N_ * D_;
  u16* vt = pbase + (size_t)5 * BH * N_ * D_;

  float* out0 = (float*)d_out;
  float* out1 = out0 + (size_t)N_ * B_ * C_;

  ConvArgs ca;
  for (int i = 0; i < 5; ++i) { ca.s[i] = in_f[i];     ca.d[i] = Xc[i];  ca.n[i] = NB * C_; }
  for (int i = 0; i < 5; ++i) { ca.s[5+i] = in_f[5+i]; ca.d[5+i] = Wc[i]; ca.n[5+i] = C_ * C_; }
  k_convert<<<dim3(2048, 10), 256, 0, stream>>>(ca);

  ProjArgs pa;
  for (int i = 0; i < 5; ++i) { pa.X[i] = Xc[i]; pa.W[i] = Wc[i]; pa.O[i] = P[i]; }
  k_proj<<<dim3(C_ / 128, NB / 128, 5), 256, 0, stream>>>(pa);

  k_transpose<<<dim3(N_ / 64, BH), 256, 0, stream>>>(P[4], vt);

  k_attn<<<dim3(N_ / 32, BH), 256, 0, stream>>>(P[0], P[1], P[2], P[3], vt, out0, out1);
}

// Round 2
// 392.296 us; speedup vs baseline: 1.0520x; 1.0501x over previous
//
#include <hip/hip_runtime.h>

#define DEVINL __device__ __forceinline__

typedef unsigned short u16;
typedef float f32x4 __attribute__((ext_vector_type(4)));
typedef __bf16 bf16x8 __attribute__((ext_vector_type(8)));

constexpr int N_ = 1024, B_ = 4, C_ = 1024, H_ = 8, D_ = 128;
constexpr int NB = N_ * B_;   // 4096 rows
constexpr int BH = B_ * H_;   // 32 head-batches

// ---------- helpers ----------
DEVINL u16 f2bf(float f) {            // RNE f32 -> bf16 (inputs finite)
  unsigned u = __builtin_bit_cast(unsigned, f);
  u += 0x7fffu + ((u >> 16) & 1u);
  return (u16)(u >> 16);
}
DEVINL float bf2f(u16 v) { return __builtin_bit_cast(float, ((unsigned)v) << 16); }

typedef __attribute__((address_space(1))) void gv_t;
typedef __attribute__((address_space(3))) void lv_t;
DEVINL void gload16(const void* g, void* l) {   // async global->LDS, 16B/lane
  __builtin_amdgcn_global_load_lds((gv_t*)(unsigned long long)g,
                                   (lv_t*)(unsigned)(unsigned long long)l, 16, 0, 0);
}
DEVINL bf16x8 ld_frag(const u16* p) { return *(const bf16x8*)p; }
DEVINL f32x4 mfma16(bf16x8 a, bf16x8 b, f32x4 c) {
  return __builtin_amdgcn_mfma_f32_16x16x32_bf16(a, b, c, 0, 0, 0);
}

// ---------- K0: fp32 -> bf16 convert ----------
struct ConvArgs { const float* s[10]; u16* d[10]; int n[10]; };

__global__ __launch_bounds__(256) void k_convert(ConvArgs a) {
  const int which = blockIdx.y;
  const int i = (blockIdx.x * 256 + threadIdx.x) * 8;
  if (i >= a.n[which]) return;
  const float* s = a.s[which] + i;
  float4 v0 = *(const float4*)s;
  float4 v1 = *(const float4*)(s + 4);
  union { uint4 v; u16 r[8]; } u;
  u.r[0] = f2bf(v0.x); u.r[1] = f2bf(v0.y); u.r[2] = f2bf(v0.z); u.r[3] = f2bf(v0.w);
  u.r[4] = f2bf(v1.x); u.r[5] = f2bf(v1.y); u.r[6] = f2bf(v1.z); u.r[7] = f2bf(v1.w);
  *(uint4*)(a.d[which] + i) = u.v;
}

// ---------- K1: projection GEMM + fused L2-norm ----------
struct ProjArgs { const u16* X[5]; const u16* W[5]; u16* O[5]; };

__global__ __launch_bounds__(256) void k_proj(ProjArgs a) {
  __shared__ u16 lA[128 * 64];
  __shared__ u16 lB[128 * 64];
  __shared__ float lred[128][2];
  const int tid = threadIdx.x, w = tid >> 6, lane = tid & 63;
  const int qd = lane >> 4, m16 = lane & 15;
  const int wr = w >> 1, wc = w & 1;
  const int r0 = blockIdx.y * 128, d0 = blockIdx.x * 128;
  const u16* __restrict__ X = a.X[blockIdx.z];
  const u16* __restrict__ W = a.W[blockIdx.z];
  u16* __restrict__ O = a.O[blockIdx.z];
  const bool donorm = blockIdx.z < 4;

  f32x4 acc[4][4];
  const f32x4 fz = {0.f, 0.f, 0.f, 0.f};
#pragma unroll
  for (int i = 0; i < 4; ++i)
#pragma unroll
    for (int j = 0; j < 4; ++j) acc[i][j] = fz;

  for (int k0 = 0; k0 < C_; k0 += 64) {
    __syncthreads();
#pragma unroll
    for (int i = 0; i < 4; ++i) {
      int p = i * 256 + tid, row = p >> 3, cp = p & 7, cl = cp ^ (row & 7);
      gload16(X + (size_t)(r0 + row) * C_ + k0 + cl * 8, &lA[p * 8]);
    }
#pragma unroll
    for (int i = 0; i < 4; ++i) {
      int p = i * 256 + tid, row = p >> 3, cp = p & 7, cl = cp ^ (row & 7);
      gload16(W + (size_t)(d0 + row) * C_ + k0 + cl * 8, &lB[p * 8]);
    }
    __syncthreads();
#pragma unroll
    for (int ks = 0; ks < 2; ++ks) {
      bf16x8 af[4], bfr[4];
#pragma unroll
      for (int t = 0; t < 4; ++t) {
        int row = wr * 64 + t * 16 + m16;
        af[t] = ld_frag(&lA[row * 64 + (((ks * 4 + qd) ^ (row & 7)) * 8)]);
        int col = wc * 64 + t * 16 + m16;
        bfr[t] = ld_frag(&lB[col * 64 + (((ks * 4 + qd) ^ (col & 7)) * 8)]);
      }
#pragma unroll
      for (int rt = 0; rt < 4; ++rt)
#pragma unroll
        for (int ct = 0; ct < 4; ++ct)
          acc[rt][ct] = mfma16(af[rt], bfr[ct], acc[rt][ct]);
    }
  }
  // fused L2-norm over the 128-col (= head dim) tile
  if (donorm) {
    float s[4][4];
#pragma unroll
    for (int rt = 0; rt < 4; ++rt)
#pragma unroll
      for (int rg = 0; rg < 4; ++rg) {
        float t = 0.f;
#pragma unroll
        for (int ct = 0; ct < 4; ++ct) t += acc[rt][ct][rg] * acc[rt][ct][rg];
        s[rt][rg] = t;
      }
#pragma unroll
    for (int off = 1; off < 16; off <<= 1)
#pragma unroll
      for (int rt = 0; rt < 4; ++rt)
#pragma unroll
        for (int rg = 0; rg < 4; ++rg) s[rt][rg] += __shfl_xor(s[rt][rg], off);
    if (m16 == 0) {
#pragma unroll
      for (int rt = 0; rt < 4; ++rt)
#pragma unroll
        for (int rg = 0; rg < 4; ++rg)
          lred[wr * 64 + rt * 16 + qd * 4 + rg][wc] = s[rt][rg];
    }
  }
  __syncthreads();
  float inv[4][4];
#pragma unroll
  for (int rt = 0; rt < 4; ++rt)
#pragma unroll
    for (int rg = 0; rg < 4; ++rg) {
      if (donorm) {
        int row = wr * 64 + rt * 16 + qd * 4 + rg;
        inv[rt][rg] = rsqrtf(lred[row][0] + lred[row][1]);
      } else inv[rt][rg] = 1.0f;
    }
  // epilogue: rows r = n*B+b ; cols = h*128+d ; write (B,H,N,D) bf16
#pragma unroll
  for (int rt = 0; rt < 4; ++rt)
#pragma unroll
    for (int ct = 0; ct < 4; ++ct)
#pragma unroll
      for (int rg = 0; rg < 4; ++rg) {
        int row = r0 + wr * 64 + rt * 16 + qd * 4 + rg;
        int col = d0 + wc * 64 + ct * 16 + m16;
        int n = row >> 2, b = row & 3, h = col >> 7, d = col & 127;
        O[(((size_t)(b * H_ + h)) * N_ + n) * D_ + d] = f2bf(acc[rt][ct][rg] * inv[rt][rg]);
      }
}

// ---------- K3: v (B,H,N,D) -> v_t (B,H,D,N) ----------
__global__ __launch_bounds__(256) void k_transpose(const u16* __restrict__ v,
                                                   u16* __restrict__ vt) {
  __shared__ u16 tile[128][65];
  const int bh = blockIdx.y, n0 = blockIdx.x * 64;
  const u16* src = v + (size_t)bh * N_ * D_;
  u16* dst = vt + (size_t)bh * D_ * N_;
  union U8 { uint4 v; u16 s[8]; };
#pragma unroll
  for (int it = 0; it < 4; ++it) {
    int c = it * 256 + threadIdx.x;
    int n = c >> 4, dc = (c & 15) * 8;
    U8 u; u.v = *(const uint4*)(src + (size_t)(n0 + n) * D_ + dc);
#pragma unroll
    for (int j = 0; j < 8; ++j) tile[dc + j][n] = u.s[j];
  }
  __syncthreads();
#pragma unroll
  for (int it = 0; it < 4; ++it) {
    int c = it * 256 + threadIdx.x;
    int d = c >> 3, nc = (c & 7) * 8;
    U8 u;
#pragma unroll
    for (int j = 0; j < 8; ++j) u.s[j] = tile[d][nc + j];
    *(uint4*)(dst + (size_t)d * N_ + n0 + nc) = u.v;
  }
}

// ---------- K4: fused stats + emit + PV, 512 threads / 8 waves ----------
// One block owns a 32-row n-strip of one (b,h). 8 waves each own a 16-row
// m-slice of each 128-m tile (rt loop gone -> pst = 64 VGPR/thread, no spill).
// Loop 1: double-buffered K staging (kr+kc), S^T once, exp -> packed bf16 regs,
// accumulate denominators. Loop 2: normalize, store attn, PV via double-
// buffered lP redistribution (one barrier per tile in each loop).
__global__ __launch_bounds__(512, 2) void k_attn(const u16* __restrict__ qr,
                                                 const u16* __restrict__ kr,
                                                 const u16* __restrict__ qc,
                                                 const u16* __restrict__ kc,
                                                 const u16* __restrict__ vt,
                                                 float* __restrict__ out0,
                                                 float* __restrict__ out1) {
  __shared__ u16 lK[2][2][128 * 128];  // 128 KB: [buf][ty] (128m x 128d)
  __shared__ u16 lP[2][32 * 136];      // 17 KB attn bf16, [n][m] A-layout (pad 8)
  __shared__ float lred[2][8][32];     // 2 KB denominator partials
  const int flat = blockIdx.x + (blockIdx.y << 5);
  const int xcd = flat & 7, kk = flat >> 3;
  const int bh = (xcd << 2) + (kk >> 5);
  const int n0 = (kk & 31) * 32;
  const int b = bh >> 3, h = bh & 7;
  const size_t base = (size_t)bh * N_ * D_;
  const int tid = threadIdx.x, w = tid >> 6, lane = tid & 63;
  const int qd = lane >> 4, m16 = lane & 15;
  const u16* ksrc[2] = {kr, kc};

  // Q fragments (B-operand layout): [type][ct 2][ks 4] = 64 VGPR
  bf16x8 qf[2][2][4];
#pragma unroll
  for (int ct = 0; ct < 2; ++ct)
#pragma unroll
    for (int ks = 0; ks < 4; ++ks) {
      size_t ro = base + (size_t)(n0 + ct * 16 + m16) * D_ + ks * 32 + qd * 8;
      qf[0][ct][ks] = ld_frag(qr + ro);
      qf[1][ct][ks] = ld_frag(qc + ro);
    }

  // packed exp(S) bf16 held in registers for the whole strip:
  // [type][mt][ct] -> 4 bf16 (uint2) = 64 VGPRs total
  uint2 pst[2][8][2];
  float psum[2][2] = {{0.f, 0.f}, {0.f, 0.f}};
  const f32x4 fz = {0.f, 0.f, 0.f, 0.f};

  // prologue: stage tile 0 into buf 0
#pragma unroll
  for (int ty = 0; ty < 2; ++ty)
#pragma unroll
    for (int i = 0; i < 4; ++i) {
      int p = i * 512 + tid, row = p >> 4, cp = p & 15, cl = cp ^ (row & 15);
      gload16(ksrc[ty] + base + (size_t)row * D_ + cl * 8, &lK[0][ty][p * 8]);
    }
  __syncthreads();

  // ---- loop 1: S once, exp -> regs, accumulate denominators ----
#pragma unroll
  for (int mt = 0; mt < 8; ++mt) {
    const int cur = mt & 1;
    if (mt < 7) {  // issue next tile's staging before compute (overlap)
      const int m0n = (mt + 1) * 128;
#pragma unroll
      for (int ty = 0; ty < 2; ++ty)
#pragma unroll
        for (int i = 0; i < 4; ++i) {
          int p = i * 512 + tid, row = p >> 4, cp = p & 15, cl = cp ^ (row & 15);
          gload16(ksrc[ty] + base + (size_t)(m0n + row) * D_ + cl * 8,
                  &lK[cur ^ 1][ty][p * 8]);
        }
    }
    const int mrow = w * 16 + m16;
#pragma unroll
    for (int ty = 0; ty < 2; ++ty) {
      bf16x8 af[4];
#pragma unroll
      for (int ks = 0; ks < 4; ++ks)
        af[ks] = ld_frag(&lK[cur][ty][mrow * 128 + (((ks * 4 + qd) ^ (mrow & 15)) * 8)]);
#pragma unroll
      for (int ct = 0; ct < 2; ++ct) {
        f32x4 acc = fz;
#pragma unroll
        for (int ks = 0; ks < 4; ++ks) acc = mfma16(af[ks], qf[ty][ct][ks], acc);
        union { uint2 u; u16 s[4]; } pk;
        float loc = 0.f;
#pragma unroll
        for (int rg = 0; rg < 4; ++rg) {
          float e = __expf(acc[rg]);
          loc += e;
          pk.s[rg] = f2bf(e);
        }
        psum[ty][ct] += loc;
        pst[ty][mt][ct] = pk.u;
      }
    }
    __syncthreads();  // drains next-tile loads; guards buf reuse
  }

  // ---- denominator reduction: over qd (shfl) then over 8 waves (LDS) ----
#pragma unroll
  for (int ty = 0; ty < 2; ++ty)
#pragma unroll
    for (int ct = 0; ct < 2; ++ct) {
      psum[ty][ct] += __shfl_xor(psum[ty][ct], 16);
      psum[ty][ct] += __shfl_xor(psum[ty][ct], 32);
    }
  if (qd == 0) {
#pragma unroll
    for (int ty = 0; ty < 2; ++ty)
#pragma unroll
      for (int ct = 0; ct < 2; ++ct) lred[ty][w][ct * 16 + m16] = psum[ty][ct];
  }
  __syncthreads();
  float il[2][2];
#pragma unroll
  for (int ty = 0; ty < 2; ++ty)
#pragma unroll
    for (int ct = 0; ct < 2; ++ct) {
      int n = ct * 16 + m16;
      float s = 0.f;
#pragma unroll
      for (int ww = 0; ww < 8; ++ww) s += lred[ty][ww][n];
      il[ty][ct] = 0.5f / s;
    }

  f32x4 xacc[2] = {fz, fz};
  float* attn = out1 + (size_t)bh * N_ * N_;
  const u16* vtb = vt + (size_t)bh * D_ * N_ + (size_t)(w * 16 + m16) * N_;

  // ---- loop 2: normalize, store attn, PV (no staging, no S recompute) ----
#pragma unroll
  for (int mt = 0; mt < 8; ++mt) {
    const int cur = mt & 1;
    const int m0 = mt * 128;
#pragma unroll
    for (int ct = 0; ct < 2; ++ct) {
      union { uint2 u; u16 s[4]; } ur, uc, pk;
      ur.u = pst[0][mt][ct];
      uc.u = pst[1][mt][ct];
      f32x4 pv;
#pragma unroll
      for (int rg = 0; rg < 4; ++rg) {
        pv[rg] = bf2f(ur.s[rg]) * il[0][ct] + bf2f(uc.s[rg]) * il[1][ct];
        pk.s[rg] = f2bf(pv[rg]);
      }
      const int nrow = n0 + ct * 16 + m16;
      const int mcol = m0 + w * 16 + qd * 4;
      *(f32x4*)(attn + (size_t)nrow * N_ + mcol) = pv;
      *(uint2*)&lP[cur][(ct * 16 + m16) * 136 + w * 16 + qd * 4] = pk.u;
    }
    __syncthreads();  // lP[cur] complete; next iter writes lP[cur^1] (dbuf)
#pragma unroll
    for (int ks = 0; ks < 4; ++ks) {
      bf16x8 pa[2];
#pragma unroll
      for (int ct = 0; ct < 2; ++ct)
        pa[ct] = ld_frag(&lP[cur][(ct * 16 + m16) * 136 + ks * 32 + qd * 8]);
      bf16x8 vb = ld_frag(vtb + m0 + ks * 32 + qd * 8);
#pragma unroll
      for (int ct = 0; ct < 2; ++ct)
        xacc[ct] = mfma16(pa[ct], vb, xacc[ct]);
    }
  }
  // epilogue: x -> out0 (N,B,C)
#pragma unroll
  for (int ct = 0; ct < 2; ++ct)
#pragma unroll
    for (int rg = 0; rg < 4; ++rg) {
      int n = n0 + ct * 16 + qd * 4 + rg;
      int d = w * 16 + m16;
      out0[((size_t)n * B_ + b) * C_ + h * 128 + d] = xacc[ct][rg];
    }
}

// ---------- launch ----------
extern "C" void kernel_launch(void* const* d_in, const int* in_sizes, int n_in,
                              void* d_out, int out_size, void* d_ws, size_t ws_size,
                              hipStream_t stream) {
  (void)in_sizes; (void)n_in; (void)out_size; (void)ws_size;
  const float* in_f[10];
  for (int i = 0; i < 10; ++i) in_f[i] = (const float*)d_in[i];

  u16* ws = (u16*)d_ws;
  u16* Xc[5], *Wc[5], *P[5];
  for (int i = 0; i < 5; ++i) Xc[i] = ws + (size_t)i * NB * C_;
  u16* wbase = ws + (size_t)5 * NB * C_;
  for (int i = 0; i < 5; ++i) Wc[i] = wbase + (size_t)i * C_ * C_;
  u16* pbase = wbase + (size_t)5 * C_ * C_;
  for (int i = 0; i < 5; ++i) P[i] = pbase + (size_t)i * BH * N_ * D_;
  u16* vt = pbase + (size_t)5 * BH * N_ * D_;

  float* out0 = (float*)d_out;
  float* out1 = out0 + (size_t)N_ * B_ * C_;

  ConvArgs ca;
  for (int i = 0; i < 5; ++i) { ca.s[i] = in_f[i];     ca.d[i] = Xc[i];  ca.n[i] = NB * C_; }
  for (int i = 0; i < 5; ++i) { ca.s[5+i] = in_f[5+i]; ca.d[5+i] = Wc[i]; ca.n[5+i] = C_ * C_; }
  k_convert<<<dim3(2048, 10), 256, 0, stream>>>(ca);

  ProjArgs pa;
  for (int i = 0; i < 5; ++i) { pa.X[i] = Xc[i]; pa.W[i] = Wc[i]; pa.O[i] = P[i]; }
  k_proj<<<dim3(C_ / 128, NB / 128, 5), 256, 0, stream>>>(pa);

  k_transpose<<<dim3(N_ / 64, BH), 256, 0, stream>>>(P[4], vt);

  k_attn<<<dim3(N_ / 32, BH), 512, 0, stream>>>(P[0], P[1], P[2], P[3], vt, out0, out1);
}